// Round 1
// baseline (552.486 us; speedup 1.0000x reference)
//
#include <hip/hip_runtime.h>
#include <hip/hip_bf16.h>
#include <math.h>

// TTrain log-contraction: B=128 chains, each a serial product of S=1024
// 64x64 matrices applied to a vector, with periodic inf-norm + log accum.
//
// Design (R1): 1 wave per batch element. Lane j owns c[j] and column j of
// the current matrix. W double-buffered in registers, prefetched 1 step
// ahead (core is L2-resident). c[i] broadcast via v_readlane (constant
// lane in unrolled loop) -> FMA with SGPR operand; no LDS in inner loop.
// Renormalize every 8 steps (mathematically identical to reference's
// per-step norm; scale drift ~2^-50 per 8 steps, safe in fp32).

#define TT_B 128
#define TT_S 1024
#define TT_D 64

__device__ __forceinline__ float bc_lane(float v, int lane) {
    // broadcast v from `lane` (compile-time constant) -> v_readlane_b32
    return __uint_as_float(__builtin_amdgcn_readlane(__float_as_uint(v), lane));
}

__global__ __launch_bounds__(64, 1) void ttrain_chain_kernel(
    const int* __restrict__ X, const float* __restrict__ core,
    const float* __restrict__ lb, const float* __restrict__ rb,
    float* __restrict__ out)
{
    const int b = blockIdx.x;
    const int j = threadIdx.x;           // 0..63, owns column j / c[j]
    const int* Xrow = X + b * TT_S;

    // ---- init: c = lb, normalize (matches reference's Z0 step) ----
    float c = lb[j];
    float Z = fabsf(c);
    #pragma unroll
    for (int m = 32; m; m >>= 1) Z = fmaxf(Z, __shfl_xor(Z, m));
    float logn = logf(Z);
    c *= (1.0f / Z);

    float wA[TT_D], wB[TT_D];

    // preload W(x_0) into wA
    {
        const int x0 = Xrow[0];
        const float* wp = core + x0 * (TT_D * TT_D) + j;
        #pragma unroll
        for (int i = 0; i < TT_D; ++i) wA[i] = wp[i * TT_D];
    }
    int x_next = Xrow[1];   // x for t+1

    #define TT_STEP(WBUF, T)                                               \
    {                                                                      \
        float a0 = 0.f, a1 = 0.f, a2 = 0.f, a3 = 0.f;                      \
        _Pragma("unroll")                                                  \
        for (int i = 0; i < TT_D; i += 4) {                                \
            a0 = fmaf(bc_lane(c, i + 0), WBUF[i + 0], a0);                 \
            a1 = fmaf(bc_lane(c, i + 1), WBUF[i + 1], a1);                 \
            a2 = fmaf(bc_lane(c, i + 2), WBUF[i + 2], a2);                 \
            a3 = fmaf(bc_lane(c, i + 3), WBUF[i + 3], a3);                 \
        }                                                                  \
        float cn = (a0 + a1) + (a2 + a3);                                  \
        if (((T) & 7) == 7) {                                              \
            float Zl = fabsf(cn);                                          \
            _Pragma("unroll")                                              \
            for (int m = 32; m; m >>= 1)                                   \
                Zl = fmaxf(Zl, __shfl_xor(Zl, m));                         \
            logn += logf(Zl);                                              \
            cn *= (1.0f / Zl);                                             \
        }                                                                  \
        c = cn;                                                            \
    }

    for (int t = 0; t < TT_S; t += 2) {
        // (1) prefetch W(x_{t+1}) -> wB
        {
            const float* wp = core + x_next * (TT_D * TT_D) + j;
            #pragma unroll
            for (int i = 0; i < TT_D; ++i) wB[i] = wp[i * TT_D];
        }
        // (2) load x_{t+2}
        const int x_next2 = Xrow[(t + 2 < TT_S) ? (t + 2) : 0];
        // (3) step t using wA  (overlaps with (1)'s loads in flight)
        TT_STEP(wA, t)
        // (4) prefetch W(x_{t+2}) -> wA
        {
            const float* wp = core + x_next2 * (TT_D * TT_D) + j;
            #pragma unroll
            for (int i = 0; i < TT_D; ++i) wA[i] = wp[i * TT_D];
        }
        // (5) load x_{t+3}
        x_next = Xrow[(t + 3 < TT_S) ? (t + 3) : 0];
        // (6) step t+1 using wB
        TT_STEP(wB, t + 1)
    }

    // ---- epilogue: out_b = 2*(logn + log|c . rb|) ----
    float dot = c * rb[j];
    #pragma unroll
    for (int m = 32; m; m >>= 1) dot += __shfl_xor(dot, m);
    if (j == 0) out[b] = 2.0f * (logn + logf(fabsf(dot)));
}

extern "C" void kernel_launch(void* const* d_in, const int* in_sizes, int n_in,
                              void* d_out, int out_size, void* d_ws, size_t ws_size,
                              hipStream_t stream) {
    const int*   X    = (const int*)d_in[0];    // [B, S] int32
    const float* core = (const float*)d_in[1];  // [d, D, D] fp32
    const float* lb   = (const float*)d_in[2];  // [D]
    const float* rb   = (const float*)d_in[3];  // [D]
    float* out = (float*)d_out;                 // [B]

    const int B = in_sizes[0] / TT_S;
    ttrain_chain_kernel<<<B, TT_D, 0, stream>>>(X, core, lb, rb, out);
}

// Round 2
// 522.779 us; speedup vs baseline: 1.0568x; 1.0568x over previous
//
#include <hip/hip_runtime.h>
#include <math.h>

// TTrain log-contraction, R2.
// B=128 chains x S=1024 serial 64x64 matvec steps. Core is L2-resident;
// problem is per-step latency, not bandwidth.
//
// R2 changes vs R1 (post-mortem: VGPR=104 -> compiler sank prefetches;
// readlane SGPR hazards):
//  - core transposed once into d_ws => lane j's column contiguous:
//    16 x global_load_dwordx4 per step instead of 64 strided dwords.
//  - c broadcast via LDS (ds_write_b32 + 16 broadcast ds_read_b128),
//    no v_readlane->SGPR->VALU hazard chain in the hot loop.
//  - X indices loaded 64-at-a-time into a lane-parallel register window;
//    per-step index via readlane of a VGPR (no per-step memory).
// Renorm every 8 steps (identical math to per-step inf-norm reference).

#define TT_S 1024
#define TT_D 64

// ---------------- transpose: coreT[x][j][i] = core[x][i][j] ----------------
__global__ __launch_bounds__(256) void tt_transpose(
    const float* __restrict__ core, float* __restrict__ coreT)
{
    __shared__ float tile[64][65];
    const int x = blockIdx.x;
    const float* src = core + x * 4096;
    float* dst = coreT + x * 4096;
    const int r0 = threadIdx.x >> 6;   // 0..3
    const int cc = threadIdx.x & 63;   // 0..63
    #pragma unroll
    for (int k = 0; k < 16; ++k)
        tile[r0 + 4 * k][cc] = src[(r0 + 4 * k) * 64 + cc];
    __syncthreads();
    #pragma unroll
    for (int k = 0; k < 16; ++k)
        dst[(r0 + 4 * k) * 64 + cc] = tile[cc][r0 + 4 * k];
}

// ---------------- main chain kernel ----------------
__global__ __launch_bounds__(64, 1) void ttrain_chain2(
    const int* __restrict__ X, const float* __restrict__ coreT,
    const float* __restrict__ lb, const float* __restrict__ rb,
    float* __restrict__ out)
{
    __shared__ float cbuf[2][64];
    const int b = blockIdx.x;
    const int j = threadIdx.x;           // owns c[j] and column j
    const int* Xrow = X + b * TT_S;

    // init: c = lb / ||lb||_inf
    float c = lb[j];
    float Z = fabsf(c);
    #pragma unroll
    for (int m = 32; m; m >>= 1) Z = fmaxf(Z, __shfl_xor(Z, m));
    float logn = logf(Z);
    c *= (1.0f / Z);

    const float* colbase = coreT + j * 64;   // + x*4096 per step

    // X window: lane j holds Xrow[tc + j]; reloaded once per 64 steps.
    int xs_cur = Xrow[j];
    int xs_nxt = Xrow[64 + j];

    float4 wA[16], wB[16];
    {
        const int x0 = Xrow[0];
        const float4* p = (const float4*)(colbase + x0 * 4096);
        #pragma unroll
        for (int k = 0; k < 16; ++k) wA[k] = p[k];
    }

    #define TT_STEP(WCUR, WNXT, SLOT, XNEXT, T)                              \
    {                                                                        \
        cbuf[SLOT][j] = c;                                                   \
        {   /* prefetch W(x_{T+1}) into WNXT */                              \
            const float4* pre = (const float4*)(colbase + (XNEXT) * 4096);   \
            _Pragma("unroll")                                                \
            for (int k = 0; k < 16; ++k) WNXT[k] = pre[k];                   \
        }                                                                    \
        asm volatile("s_waitcnt lgkmcnt(0)" ::: "memory");                   \
        float a0 = 0.f, a1 = 0.f, a2 = 0.f, a3 = 0.f;                        \
        const float4* cb = (const float4*)cbuf[SLOT];                        \
        _Pragma("unroll")                                                    \
        for (int k = 0; k < 16; ++k) {                                       \
            float4 cv = cb[k];   /* broadcast: all lanes same addr */        \
            a0 = fmaf(cv.x, WCUR[k].x, a0);                                  \
            a1 = fmaf(cv.y, WCUR[k].y, a1);                                  \
            a2 = fmaf(cv.z, WCUR[k].z, a2);                                  \
            a3 = fmaf(cv.w, WCUR[k].w, a3);                                  \
        }                                                                    \
        float cn = (a0 + a1) + (a2 + a3);                                    \
        if (((T) & 7) == 7) {                                                \
            float Zl = fabsf(cn);                                            \
            _Pragma("unroll")                                                \
            for (int m = 32; m; m >>= 1)                                     \
                Zl = fmaxf(Zl, __shfl_xor(Zl, m));                           \
            logn += logf(Zl);                                                \
            cn *= (1.0f / Zl);                                               \
        }                                                                    \
        c = cn;                                                              \
    }

    for (int tc = 0; tc < TT_S; tc += 64) {
        #pragma unroll 1
        for (int u = 0; u < 64; u += 2) {
            // step t = tc+u (even): uses wA, prefetch x_{t+1} -> wB
            const int x1 = __builtin_amdgcn_readlane(xs_cur, u + 1); // u+1<=63
            TT_STEP(wA, wB, 0, x1, tc + u)
            // step t+1 (odd): uses wB, prefetch x_{t+2} -> wA
            const int src2 = (u + 2 < 64) ? xs_cur : xs_nxt;
            const int x2 = __builtin_amdgcn_readlane(src2, (u + 2) & 63);
            TT_STEP(wB, wA, 1, x2, tc + u + 1)
        }
        xs_cur = xs_nxt;
        const int nc = tc + 128;
        xs_nxt = Xrow[((nc < TT_S) ? nc : 0) + j];
    }
    #undef TT_STEP

    // epilogue: out_b = 2*(logn + log|c . rb|)
    float dot = c * rb[j];
    #pragma unroll
    for (int m = 32; m; m >>= 1) dot += __shfl_xor(dot, m);
    if (j == 0) out[b] = 2.0f * (logn + logf(fabsf(dot)));
}

// ---------------- fallback (R1 kernel) if d_ws is too small ----------------
__device__ __forceinline__ float bc_lane(float v, int lane) {
    return __uint_as_float(__builtin_amdgcn_readlane(__float_as_uint(v), lane));
}

__global__ __launch_bounds__(64, 1) void ttrain_chain_fb(
    const int* __restrict__ X, const float* __restrict__ core,
    const float* __restrict__ lb, const float* __restrict__ rb,
    float* __restrict__ out)
{
    const int b = blockIdx.x;
    const int j = threadIdx.x;
    const int* Xrow = X + b * TT_S;

    float c = lb[j];
    float Z = fabsf(c);
    #pragma unroll
    for (int m = 32; m; m >>= 1) Z = fmaxf(Z, __shfl_xor(Z, m));
    float logn = logf(Z);
    c *= (1.0f / Z);

    float wA[TT_D], wB[TT_D];
    {
        const int x0 = Xrow[0];
        const float* wp = core + x0 * (TT_D * TT_D) + j;
        #pragma unroll
        for (int i = 0; i < TT_D; ++i) wA[i] = wp[i * TT_D];
    }
    int x_next = Xrow[1];

    #define TT_STEP_FB(WBUF, T)                                            \
    {                                                                      \
        float a0 = 0.f, a1 = 0.f, a2 = 0.f, a3 = 0.f;                      \
        _Pragma("unroll")                                                  \
        for (int i = 0; i < TT_D; i += 4) {                                \
            a0 = fmaf(bc_lane(c, i + 0), WBUF[i + 0], a0);                 \
            a1 = fmaf(bc_lane(c, i + 1), WBUF[i + 1], a1);                 \
            a2 = fmaf(bc_lane(c, i + 2), WBUF[i + 2], a2);                 \
            a3 = fmaf(bc_lane(c, i + 3), WBUF[i + 3], a3);                 \
        }                                                                  \
        float cn = (a0 + a1) + (a2 + a3);                                  \
        if (((T) & 7) == 7) {                                              \
            float Zl = fabsf(cn);                                          \
            _Pragma("unroll")                                              \
            for (int m = 32; m; m >>= 1)                                   \
                Zl = fmaxf(Zl, __shfl_xor(Zl, m));                         \
            logn += logf(Zl);                                              \
            cn *= (1.0f / Zl);                                             \
        }                                                                  \
        c = cn;                                                            \
    }

    for (int t = 0; t < TT_S; t += 2) {
        {
            const float* wp = core + x_next * (TT_D * TT_D) + j;
            #pragma unroll
            for (int i = 0; i < TT_D; ++i) wB[i] = wp[i * TT_D];
        }
        const int x_next2 = Xrow[(t + 2 < TT_S) ? (t + 2) : 0];
        TT_STEP_FB(wA, t)
        {
            const float* wp = core + x_next2 * (TT_D * TT_D) + j;
            #pragma unroll
            for (int i = 0; i < TT_D; ++i) wA[i] = wp[i * TT_D];
        }
        x_next = Xrow[(t + 3 < TT_S) ? (t + 3) : 0];
        TT_STEP_FB(wB, t + 1)
    }
    #undef TT_STEP_FB

    float dot = c * rb[j];
    #pragma unroll
    for (int m = 32; m; m >>= 1) dot += __shfl_xor(dot, m);
    if (j == 0) out[b] = 2.0f * (logn + logf(fabsf(dot)));
}

extern "C" void kernel_launch(void* const* d_in, const int* in_sizes, int n_in,
                              void* d_out, int out_size, void* d_ws, size_t ws_size,
                              hipStream_t stream) {
    const int*   X    = (const int*)d_in[0];    // [B, S] int32
    const float* core = (const float*)d_in[1];  // [d, D, D] fp32
    const float* lb   = (const float*)d_in[2];  // [D]
    const float* rb   = (const float*)d_in[3];  // [D]
    float* out = (float*)d_out;                 // [B]

    const int B = in_sizes[0] / TT_S;
    const size_t need = (size_t)64 * TT_D * TT_D * sizeof(float);  // 1 MiB

    if (ws_size >= need) {
        float* coreT = (float*)d_ws;
        tt_transpose<<<64, 256, 0, stream>>>(core, coreT);
        ttrain_chain2<<<B, TT_D, 0, stream>>>(X, coreT, lb, rb, out);
    } else {
        ttrain_chain_fb<<<B, TT_D, 0, stream>>>(X, core, lb, rb, out);
    }
}

// Round 3
// 155.049 us; speedup vs baseline: 3.5633x; 3.3717x over previous
//
#include <hip/hip_runtime.h>
#include <math.h>

// TTrain log-contraction, R3: chunk-parallel MFMA matrix products.
// lb . W1 . ... . W1024 . rb  ==  lb . P0 . P1 ... P15 . rb,
// P_chunk = prod of 64 gathered 64x64 matrices, computed per-wave with
// v_mfma_f32_16x16x32_bf16, M accumulated right-to-left (M <- W_t * M) so
// the streamed operand (W_t, from a prebuilt A-fragment table) needs no
// transform; only M needs C-layout -> B-layout, via a 9KB LDS round trip.
// Inf-norm renorm every 8 steps (reassociated; mathematically identical).

#define TT_S 1024
#define TT_D 64

typedef __attribute__((ext_vector_type(8))) short short8;     // 8 bf16
typedef __attribute__((ext_vector_type(4))) float float4v;    // MFMA C/D
typedef __attribute__((ext_vector_type(2))) unsigned int uint2v;

__device__ __forceinline__ unsigned bf16_rne(float f) {
    unsigned u = __float_as_uint(f);
    return (u + 0x7FFFu + ((u >> 16) & 1u)) >> 16;
}

// ---------- prep: build bf16 A-frag and B-frag tables for all 64 cores ----
// A-frag f=I*2+K': lane l holds A[16I + (l&15)][32K' + (l>>4)*8 + j]
// B-frag f=K'*4+J: lane l holds B[32K' + (l>>4)*8 + j][16J + (l&15)]
__global__ __launch_bounds__(64) void tt_prep(
    const float* __restrict__ core, short* __restrict__ tblA,
    short* __restrict__ tblB)
{
    const int x = blockIdx.x, l = threadIdx.x;
    const int n = l & 15, q = l >> 4;
    const float* W = core + x * 4096;
    #pragma unroll
    for (int I = 0; I < 4; ++I)
        #pragma unroll
        for (int Kp = 0; Kp < 2; ++Kp) {
            short8 v;
            const int row = 16 * I + n, k0 = 32 * Kp + 8 * q;
            #pragma unroll
            for (int j = 0; j < 8; ++j) v[j] = (short)bf16_rne(W[row * 64 + k0 + j]);
            *(short8*)(tblA + ((size_t)(x * 8 + I * 2 + Kp) * 64 + l) * 8) = v;
        }
    #pragma unroll
    for (int Kp = 0; Kp < 2; ++Kp)
        #pragma unroll
        for (int J = 0; J < 4; ++J) {
            short8 v;
            const int col = 16 * J + n, k0 = 32 * Kp + 8 * q;
            #pragma unroll
            for (int j = 0; j < 8; ++j) v[j] = (short)bf16_rne(W[(k0 + j) * 64 + col]);
            *(short8*)(tblB + ((size_t)(x * 8 + Kp * 4 + J) * 64 + l) * 8) = v;
        }
}

// ---------- stage 1: one wave per chunk of 64 matrices ----------
__global__ __launch_bounds__(64, 2) void tt_stage1(
    const int* __restrict__ X, const short* __restrict__ tblA,
    const short* __restrict__ tblB, float* __restrict__ PT,
    float* __restrict__ ln1)
{
    __shared__ short mt[64 * 72];          // M^T bf16, row-stride 72 (pad)
    const int w = blockIdx.x;
    const int b = w >> 4, chunk = w & 15;
    const int l = threadIdx.x, n = l & 15, q = l >> 4;
    const int t0 = chunk * 64;
    const int xv = X[b * TT_S + t0 + l];   // 64 chunk indices, one per lane

    // init M = W[x_{63}] directly in B-frag layout
    short8 Bf[8];
    {
        const int x63 = __builtin_amdgcn_readfirstlane(__shfl(xv, 63));
        const short8* p = (const short8*)(tblB + (size_t)x63 * 4096 + l * 8);
        #pragma unroll
        for (int f = 0; f < 8; ++f) Bf[f] = p[f * 64];
    }
    float4v acc[4][4];
    float logn = 0.f;
    const float4v zero = {0.f, 0.f, 0.f, 0.f};

    #pragma unroll 1
    for (int s = 0; s < 63; ++s) {
        const int t = 62 - s;
        // (1) stream A-frags of W[x_t] (issued early; transform covers latency)
        const int xt = __builtin_amdgcn_readfirstlane(__shfl(xv, t));
        const short8* pa = (const short8*)(tblA + (size_t)xt * 4096 + l * 8);
        short8 Af[8];
        #pragma unroll
        for (int f = 0; f < 8; ++f) Af[f] = pa[f * 64];

        // (2) transform previous C (acc) -> B-frags of M via LDS
        if (s > 0) {
            if ((s & 7) == 0) {            // renorm every 8 multiplies
                float Z = 0.f;
                #pragma unroll
                for (int I = 0; I < 4; ++I)
                    #pragma unroll
                    for (int J = 0; J < 4; ++J)
                        #pragma unroll
                        for (int r = 0; r < 4; ++r)
                            Z = fmaxf(Z, fabsf(acc[I][J][r]));
                #pragma unroll
                for (int m = 32; m; m >>= 1) Z = fmaxf(Z, __shfl_xor(Z, m));
                logn += logf(Z);
                const float rZ = 1.0f / Z;
                #pragma unroll
                for (int I = 0; I < 4; ++I)
                    #pragma unroll
                    for (int J = 0; J < 4; ++J)
                        #pragma unroll
                        for (int r = 0; r < 4; ++r) acc[I][J][r] *= rZ;
            }
            // pack: bf16-truncate pairs of rows -> one dword; write M^T
            #pragma unroll
            for (int I = 0; I < 4; ++I)
                #pragma unroll
                for (int J = 0; J < 4; ++J) {
                    const float4v v = acc[I][J];
                    uint2v dd;
                    dd[0] = __builtin_amdgcn_perm(__float_as_uint(v[1]),
                                                  __float_as_uint(v[0]), 0x07060302u);
                    dd[1] = __builtin_amdgcn_perm(__float_as_uint(v[3]),
                                                  __float_as_uint(v[2]), 0x07060302u);
                    *(uint2v*)(mt + (16 * J + n) * 72 + 16 * I + 4 * q) = dd;
                }
            asm volatile("s_waitcnt lgkmcnt(0)" ::: "memory");
            #pragma unroll
            for (int Kp = 0; Kp < 2; ++Kp)
                #pragma unroll
                for (int J = 0; J < 4; ++J)
                    Bf[Kp * 4 + J] =
                        *(const short8*)(mt + (16 * J + n) * 72 + 32 * Kp + 8 * q);
        }

        // (3) MFMA: acc = W[x_t] * M   (16 tiles, K accumulated over 2 frags)
        #pragma unroll
        for (int I = 0; I < 4; ++I)
            #pragma unroll
            for (int J = 0; J < 4; ++J) {
                float4v c0 = __builtin_amdgcn_mfma_f32_16x16x32_bf16(
                    Af[I * 2 + 0], Bf[0 * 4 + J], zero, 0, 0, 0);
                acc[I][J] = __builtin_amdgcn_mfma_f32_16x16x32_bf16(
                    Af[I * 2 + 1], Bf[1 * 4 + J], c0, 0, 0, 0);
            }
    }

    // final renorm + write P^T (fp32) and chunk log-norm
    {
        float Z = 0.f;
        #pragma unroll
        for (int I = 0; I < 4; ++I)
            #pragma unroll
            for (int J = 0; J < 4; ++J)
                #pragma unroll
                for (int r = 0; r < 4; ++r) Z = fmaxf(Z, fabsf(acc[I][J][r]));
        #pragma unroll
        for (int m = 32; m; m >>= 1) Z = fmaxf(Z, __shfl_xor(Z, m));
        logn += logf(Z);
        const float rZ = 1.0f / Z;
        float* base = PT + (size_t)w * 4096;
        #pragma unroll
        for (int I = 0; I < 4; ++I)
            #pragma unroll
            for (int J = 0; J < 4; ++J) {
                float4v v = acc[I][J];
                #pragma unroll
                for (int r = 0; r < 4; ++r) v[r] *= rZ;
                *(float4v*)(base + (16 * J + n) * 64 + 16 * I + 4 * q) = v;
            }
        if (l == 0) ln1[w] = logn;
    }
}

// ---------- stage 2: combine 16 chunk matrices per batch ----------
__global__ __launch_bounds__(64) void tt_stage2(
    const float* __restrict__ PT, const float* __restrict__ ln1,
    const float* __restrict__ lb, const float* __restrict__ rb,
    float* __restrict__ out)
{
    __shared__ float cb[64];
    const int b = blockIdx.x, j = threadIdx.x;

    float c = lb[j];
    float Z = fabsf(c);
    #pragma unroll
    for (int m = 32; m; m >>= 1) Z = fmaxf(Z, __shfl_xor(Z, m));
    float logn = logf(Z);
    c *= (1.0f / Z);

    float ln = (j < 16) ? ln1[b * 16 + j] : 0.f;
    #pragma unroll
    for (int m = 32; m; m >>= 1) ln += __shfl_xor(ln, m);
    logn += ln;

    const float* base = PT + (size_t)b * 16 * 4096 + j * 64;  // PT[j][:] = P[:,j]
    float4v wb[16];
    #pragma unroll
    for (int f = 0; f < 16; ++f) wb[f] = ((const float4v*)base)[f];

    #pragma unroll 1
    for (int k = 0; k < 16; ++k) {
        float4v wn[16];
        const float4v* nb = (const float4v*)(base + (size_t)((k + 1) & 15) * 4096);
        #pragma unroll
        for (int f = 0; f < 16; ++f) wn[f] = nb[f];

        cb[j] = c;
        asm volatile("s_waitcnt lgkmcnt(0)" ::: "memory");
        float a0 = 0.f, a1 = 0.f, a2 = 0.f, a3 = 0.f;
        #pragma unroll
        for (int f = 0; f < 16; ++f) {
            const float4v cv = *(const float4v*)(cb + 4 * f);
            a0 = fmaf(cv[0], wb[f][0], a0);
            a1 = fmaf(cv[1], wb[f][1], a1);
            a2 = fmaf(cv[2], wb[f][2], a2);
            a3 = fmaf(cv[3], wb[f][3], a3);
        }
        float cn = (a0 + a1) + (a2 + a3);
        float Zl = fabsf(cn);
        #pragma unroll
        for (int m = 32; m; m >>= 1) Zl = fmaxf(Zl, __shfl_xor(Zl, m));
        logn += logf(Zl);
        c = cn * (1.0f / Zl);
        #pragma unroll
        for (int f = 0; f < 16; ++f) wb[f] = wn[f];
    }

    float dot = c * rb[j];
    #pragma unroll
    for (int m = 32; m; m >>= 1) dot += __shfl_xor(dot, m);
    if (j == 0) out[b] = 2.0f * (logn + logf(fabsf(dot)));
}

// ---------------- fallback (R2 kernel) if d_ws is too small ----------------
__global__ __launch_bounds__(256) void tt_transpose(
    const float* __restrict__ core, float* __restrict__ coreT)
{
    __shared__ float tile[64][65];
    const int x = blockIdx.x;
    const float* src = core + x * 4096;
    float* dst = coreT + x * 4096;
    const int r0 = threadIdx.x >> 6, cc = threadIdx.x & 63;
    #pragma unroll
    for (int k = 0; k < 16; ++k) tile[r0 + 4 * k][cc] = src[(r0 + 4 * k) * 64 + cc];
    __syncthreads();
    #pragma unroll
    for (int k = 0; k < 16; ++k) dst[(r0 + 4 * k) * 64 + cc] = tile[cc][r0 + 4 * k];
}

__global__ __launch_bounds__(64, 1) void ttrain_chain2(
    const int* __restrict__ X, const float* __restrict__ coreT,
    const float* __restrict__ lb, const float* __restrict__ rb,
    float* __restrict__ out)
{
    __shared__ float cbuf[2][64];
    const int b = blockIdx.x, j = threadIdx.x;
    const int* Xrow = X + b * TT_S;
    float c = lb[j];
    float Z = fabsf(c);
    #pragma unroll
    for (int m = 32; m; m >>= 1) Z = fmaxf(Z, __shfl_xor(Z, m));
    float logn = logf(Z);
    c *= (1.0f / Z);
    const float* colbase = coreT + j * 64;
    int xs_cur = Xrow[j];
    int xs_nxt = Xrow[64 + j];
    float4 wA[16], wB[16];
    {
        const int x0 = Xrow[0];
        const float4* p = (const float4*)(colbase + x0 * 4096);
        #pragma unroll
        for (int k = 0; k < 16; ++k) wA[k] = p[k];
    }
    #define TT_STEP(WCUR, WNXT, SLOT, XNEXT, T)                              \
    {                                                                        \
        cbuf[SLOT][j] = c;                                                   \
        {                                                                    \
            const float4* pre = (const float4*)(colbase + (XNEXT) * 4096);   \
            _Pragma("unroll")                                                \
            for (int k = 0; k < 16; ++k) WNXT[k] = pre[k];                   \
        }                                                                    \
        asm volatile("s_waitcnt lgkmcnt(0)" ::: "memory");                   \
        float a0 = 0.f, a1 = 0.f, a2 = 0.f, a3 = 0.f;                        \
        const float4* cb2 = (const float4*)cbuf[SLOT];                       \
        _Pragma("unroll")                                                    \
        for (int k = 0; k < 16; ++k) {                                       \
            float4 cv = cb2[k];                                              \
            a0 = fmaf(cv.x, WCUR[k].x, a0);                                  \
            a1 = fmaf(cv.y, WCUR[k].y, a1);                                  \
            a2 = fmaf(cv.z, WCUR[k].z, a2);                                  \
            a3 = fmaf(cv.w, WCUR[k].w, a3);                                  \
        }                                                                    \
        float cn = (a0 + a1) + (a2 + a3);                                    \
        if (((T) & 7) == 7) {                                                \
            float Zl = fabsf(cn);                                            \
            _Pragma("unroll")                                                \
            for (int m = 32; m; m >>= 1) Zl = fmaxf(Zl, __shfl_xor(Zl, m));  \
            logn += logf(Zl);                                                \
            cn *= (1.0f / Zl);                                               \
        }                                                                    \
        c = cn;                                                              \
    }
    for (int tc = 0; tc < TT_S; tc += 64) {
        #pragma unroll 1
        for (int u = 0; u < 64; u += 2) {
            const int x1 = __builtin_amdgcn_readlane(xs_cur, u + 1);
            TT_STEP(wA, wB, 0, x1, tc + u)
            const int src2 = (u + 2 < 64) ? xs_cur : xs_nxt;
            const int x2 = __builtin_amdgcn_readlane(src2, (u + 2) & 63);
            TT_STEP(wB, wA, 1, x2, tc + u + 1)
        }
        xs_cur = xs_nxt;
        const int nc = tc + 128;
        xs_nxt = Xrow[((nc < TT_S) ? nc : 0) + j];
    }
    #undef TT_STEP
    float dot = c * rb[j];
    #pragma unroll
    for (int m = 32; m; m >>= 1) dot += __shfl_xor(dot, m);
    if (j == 0) out[b] = 2.0f * (logn + logf(fabsf(dot)));
}

extern "C" void kernel_launch(void* const* d_in, const int* in_sizes, int n_in,
                              void* d_out, int out_size, void* d_ws, size_t ws_size,
                              hipStream_t stream) {
    const int*   X    = (const int*)d_in[0];    // [B, S] int32
    const float* core = (const float*)d_in[1];  // [d, D, D] fp32
    const float* lb   = (const float*)d_in[2];  // [D]
    const float* rb   = (const float*)d_in[3];  // [D]
    float* out = (float*)d_out;                 // [B]

    const int B = in_sizes[0] / TT_S;
    const size_t tblBytes = (size_t)64 * 8 * 64 * 8 * sizeof(short);  // 512KB each
    const size_t ptBytes  = (size_t)B * 16 * 4096 * sizeof(float);    // 32MB @B=128
    const size_t lnBytes  = (size_t)B * 16 * sizeof(float);
    const size_t need = 2 * tblBytes + ptBytes + lnBytes;

    if (ws_size >= need) {
        char* w = (char*)d_ws;
        short* tblA = (short*)w;
        short* tblB = (short*)(w + tblBytes);
        float* PT   = (float*)(w + 2 * tblBytes);
        float* ln1  = (float*)(w + 2 * tblBytes + ptBytes);
        tt_prep<<<64, 64, 0, stream>>>(core, tblA, tblB);
        tt_stage1<<<B * 16, 64, 0, stream>>>(X, tblA, tblB, PT, ln1);
        tt_stage2<<<B, 64, 0, stream>>>(PT, ln1, lb, rb, out);
    } else if (ws_size >= (size_t)64 * 4096 * sizeof(float)) {
        float* coreT = (float*)d_ws;
        tt_transpose<<<64, 256, 0, stream>>>(core, coreT);
        ttrain_chain2<<<B, TT_D, 0, stream>>>(X, coreT, lb, rb, out);
    }
}

// Round 4
// 143.843 us; speedup vs baseline: 3.8409x; 1.0779x over previous
//
#include <hip/hip_runtime.h>
#include <math.h>

// TTrain log-contraction, R4: chunk-parallel MFMA with ZERO-SHUFFLE feedback.
//
// R3 post-mortem: stage1 DS-pipe-bound (16 KB LDS round trip per matrix
// product = 2.06 GB total = 40 us floor, + 1.2e7 bank conflicts).
//
// R4: exploit that MFMA C/D layout (col=lane&15, row=4q+reg) and B-operand
// layout (col=lane&15, k=8q+j) share the same col->lane map. Feeding packed
// C registers as the next B operand presents M~ = P_phi * M for the fixed
// lane-independent row permutation
//     phi(32Kp + 8q + j) = 32Kp + 16*(j>>2) + 4q + (j&3).
// We bake phi into the tables: A'-table = W with columns permuted by phi,
// Binit-table = W with rows permuted by phi. Then
//     sum_k W[m][phi(k)] * M[phi(k)][n] = (W*M)[m][n]
// exactly -> per-step transform = 32 in-lane v_perm packs. No LDS, no
// barriers, no cross-lane ops in the hot loop. X indices via scalar loads.
// Renorm every 8 products (identical math to reference's per-step inf-norm).

#define TT_S 1024
#define TT_D 64

typedef __attribute__((ext_vector_type(8))) short short8;     // 8 bf16
typedef __attribute__((ext_vector_type(4))) float float4v;    // MFMA C/D
typedef __attribute__((ext_vector_type(4))) unsigned uint4v;

static __device__ __forceinline__ short8 as_short8(uint4v u) {
    union { uint4v u; short8 s; } x; x.u = u; return x.s;
}

// ---------- prep: phi-permuted A' table + phi-row-permuted Binit table ----
// A'-frag f=I*2+Kp: lane l=(n,q) holds W[16I+n][phi(32Kp+8q+j)], j=0..7
// Binit-frag f=Kp*4+J: lane l holds W[phi(32Kp+8q+j)][16J+n]
// phi offset: 32Kp + 16*(j>>2) + 4q + (j&3)
__global__ __launch_bounds__(64) void tt_prep(
    const float* __restrict__ core, short* __restrict__ tblA,
    short* __restrict__ tblBt)
{
    const int x = blockIdx.x, l = threadIdx.x;
    const int n = l & 15, q = l >> 4;
    const float* W = core + x * 4096;

    #pragma unroll
    for (int I = 0; I < 4; ++I)
        #pragma unroll
        for (int Kp = 0; Kp < 2; ++Kp) {
            short8 v;
            const int row = 16 * I + n;
            const int c0 = 32 * Kp + 4 * q;
            #pragma unroll
            for (int j = 0; j < 8; ++j) {
                const int col = c0 + 16 * (j >> 2) + (j & 3);
                v[j] = (short)(__float_as_uint(W[row * 64 + col]) >> 16);
            }
            *(short8*)(tblA + ((size_t)(x * 8 + I * 2 + Kp) * 64 + l) * 8) = v;
        }
    #pragma unroll
    for (int Kp = 0; Kp < 2; ++Kp)
        #pragma unroll
        for (int J = 0; J < 4; ++J) {
            short8 v;
            const int col = 16 * J + n;
            const int r0 = 32 * Kp + 4 * q;
            #pragma unroll
            for (int j = 0; j < 8; ++j) {
                const int row = r0 + 16 * (j >> 2) + (j & 3);
                v[j] = (short)(__float_as_uint(W[row * 64 + col]) >> 16);
            }
            *(short8*)(tblBt + ((size_t)(x * 8 + Kp * 4 + J) * 64 + l) * 8) = v;
        }
}

// ---------- stage 1: one wave per chunk of 64 matrices, no LDS ----------
__global__ __launch_bounds__(64, 2) void tt_stage1(
    const int* __restrict__ X, const short* __restrict__ tblA,
    const short* __restrict__ tblBt, float* __restrict__ PT,
    float* __restrict__ ln1)
{
    const int w = blockIdx.x;
    const int b = w >> 4, chunk = w & 15;
    const int l = threadIdx.x, n = l & 15, q = l >> 4;
    const int* Xc = X + b * TT_S + chunk * 64;   // wave-uniform -> s_load

    const float4v zero = {0.f, 0.f, 0.f, 0.f};
    float4v acc[4][4];
    short8 Bf[8], A0[8], A1[8];
    float logn = 0.f;

    #define LOAD_FRAGS(DST, TBL, XIDX)                                        \
    {   const short8* p_ = (const short8*)((TBL) + (size_t)(XIDX) * 4096) + l; \
        _Pragma("unroll")                                                     \
        for (int f_ = 0; f_ < 8; ++f_) (DST)[f_] = p_[f_ * 64]; }

    #define MFMA_ALL(ABUF)                                                    \
        _Pragma("unroll")                                                     \
        for (int I_ = 0; I_ < 4; ++I_)                                        \
            _Pragma("unroll")                                                 \
            for (int J_ = 0; J_ < 4; ++J_) {                                  \
                float4v c0_ = __builtin_amdgcn_mfma_f32_16x16x32_bf16(        \
                    (ABUF)[2 * I_ + 0], Bf[J_], zero, 0, 0, 0);               \
                acc[I_][J_] = __builtin_amdgcn_mfma_f32_16x16x32_bf16(        \
                    (ABUF)[2 * I_ + 1], Bf[4 + J_], c0_, 0, 0, 0);            \
            }

    // pack acc (C layout, f32) -> Bf (B layout of phi-permuted M), in-lane
    #define PACK_BF()                                                         \
        _Pragma("unroll")                                                     \
        for (int Kp_ = 0; Kp_ < 2; ++Kp_)                                     \
            _Pragma("unroll")                                                 \
            for (int J_ = 0; J_ < 4; ++J_) {                                  \
                uint4v u_;                                                    \
                u_[0] = __builtin_amdgcn_perm(                                \
                    __float_as_uint(acc[2 * Kp_][J_][1]),                     \
                    __float_as_uint(acc[2 * Kp_][J_][0]), 0x07060302u);       \
                u_[1] = __builtin_amdgcn_perm(                                \
                    __float_as_uint(acc[2 * Kp_][J_][3]),                     \
                    __float_as_uint(acc[2 * Kp_][J_][2]), 0x07060302u);       \
                u_[2] = __builtin_amdgcn_perm(                                \
                    __float_as_uint(acc[2 * Kp_ + 1][J_][1]),                 \
                    __float_as_uint(acc[2 * Kp_ + 1][J_][0]), 0x07060302u);   \
                u_[3] = __builtin_amdgcn_perm(                                \
                    __float_as_uint(acc[2 * Kp_ + 1][J_][3]),                 \
                    __float_as_uint(acc[2 * Kp_ + 1][J_][2]), 0x07060302u);   \
                Bf[Kp_ * 4 + J_] = as_short8(u_);                             \
            }

    #define RENORM()                                                          \
    {   float Z_ = 0.f;                                                       \
        _Pragma("unroll")                                                     \
        for (int I_ = 0; I_ < 4; ++I_)                                        \
            _Pragma("unroll")                                                 \
            for (int J_ = 0; J_ < 4; ++J_)                                    \
                _Pragma("unroll")                                             \
                for (int r_ = 0; r_ < 4; ++r_)                                \
                    Z_ = fmaxf(Z_, fabsf(acc[I_][J_][r_]));                   \
        _Pragma("unroll")                                                     \
        for (int m_ = 32; m_; m_ >>= 1) Z_ = fmaxf(Z_, __shfl_xor(Z_, m_));   \
        logn += logf(Z_);                                                     \
        const float rZ_ = 1.0f / Z_;                                          \
        _Pragma("unroll")                                                     \
        for (int I_ = 0; I_ < 4; ++I_)                                        \
            _Pragma("unroll")                                                 \
            for (int J_ = 0; J_ < 4; ++J_)                                    \
                _Pragma("unroll")                                             \
                for (int r_ = 0; r_ < 4; ++r_) acc[I_][J_][r_] *= rZ_; }

    // init: Bf = Binit(x63); A0 = A'(x62); A1 = A'(x61)
    LOAD_FRAGS(Bf, tblBt, Xc[63])
    LOAD_FRAGS(A0, tblA, Xc[62])
    LOAD_FRAGS(A1, tblA, Xc[61])

    // s = 0 (t = 62): acc = W62 * W63; refill A0 for t = 60
    MFMA_ALL(A0)
    LOAD_FRAGS(A0, tblA, Xc[60])

    #pragma unroll 1
    for (int it = 0; it < 31; ++it) {
        // s = 2it+1 (odd, never renorm), consumes A1, refills A1 for t-2
        PACK_BF()
        MFMA_ALL(A1)
        {
            const int tn = 59 - 2 * it;
            LOAD_FRAGS(A1, tblA, Xc[tn < 0 ? 0 : tn])
        }
        // s = 2it+2 (even), consumes A0, refills A0
        if (((2 * it + 2) & 7) == 0) RENORM()
        PACK_BF()
        MFMA_ALL(A0)
        {
            const int tn = 58 - 2 * it;
            LOAD_FRAGS(A0, tblA, Xc[tn < 0 ? 0 : tn])
        }
    }

    // final renorm + write P^T (fp32, column-major P) and chunk log-norm
    {
        float Z = 0.f;
        #pragma unroll
        for (int I = 0; I < 4; ++I)
            #pragma unroll
            for (int J = 0; J < 4; ++J)
                #pragma unroll
                for (int r = 0; r < 4; ++r) Z = fmaxf(Z, fabsf(acc[I][J][r]));
        #pragma unroll
        for (int m = 32; m; m >>= 1) Z = fmaxf(Z, __shfl_xor(Z, m));
        logn += logf(Z);
        const float rZ = 1.0f / Z;
        float* base = PT + (size_t)w * 4096;
        #pragma unroll
        for (int I = 0; I < 4; ++I)
            #pragma unroll
            for (int J = 0; J < 4; ++J) {
                float4v v = acc[I][J];
                #pragma unroll
                for (int r = 0; r < 4; ++r) v[r] *= rZ;
                *(float4v*)(base + (16 * J + n) * 64 + 16 * I + 4 * q) = v;
            }
        if (l == 0) ln1[w] = logn;
    }
    #undef LOAD_FRAGS
    #undef MFMA_ALL
    #undef PACK_BF
    #undef RENORM
}

// ---------- stage 2: combine 16 chunk matrices per batch (from R3) ----------
__global__ __launch_bounds__(64) void tt_stage2(
    const float* __restrict__ PT, const float* __restrict__ ln1,
    const float* __restrict__ lb, const float* __restrict__ rb,
    float* __restrict__ out)
{
    __shared__ float cb[64];
    const int b = blockIdx.x, j = threadIdx.x;

    float c = lb[j];
    float Z = fabsf(c);
    #pragma unroll
    for (int m = 32; m; m >>= 1) Z = fmaxf(Z, __shfl_xor(Z, m));
    float logn = logf(Z);
    c *= (1.0f / Z);

    float ln = (j < 16) ? ln1[b * 16 + j] : 0.f;
    #pragma unroll
    for (int m = 32; m; m >>= 1) ln += __shfl_xor(ln, m);
    logn += ln;

    const float* base = PT + (size_t)b * 16 * 4096 + j * 64;  // PT[j][:] = P[:,j]
    float4v wb[16];
    #pragma unroll
    for (int f = 0; f < 16; ++f) wb[f] = ((const float4v*)base)[f];

    #pragma unroll 1
    for (int k = 0; k < 16; ++k) {
        float4v wn[16];
        const float4v* nb = (const float4v*)(base + (size_t)((k + 1) & 15) * 4096);
        #pragma unroll
        for (int f = 0; f < 16; ++f) wn[f] = nb[f];

        cb[j] = c;
        asm volatile("s_waitcnt lgkmcnt(0)" ::: "memory");
        float a0 = 0.f, a1 = 0.f, a2 = 0.f, a3 = 0.f;
        #pragma unroll
        for (int f = 0; f < 16; ++f) {
            const float4v cv = *(const float4v*)(cb + 4 * f);
            a0 = fmaf(cv[0], wb[f][0], a0);
            a1 = fmaf(cv[1], wb[f][1], a1);
            a2 = fmaf(cv[2], wb[f][2], a2);
            a3 = fmaf(cv[3], wb[f][3], a3);
        }
        float cn = (a0 + a1) + (a2 + a3);
        float Zl = fabsf(cn);
        #pragma unroll
        for (int m = 32; m; m >>= 1) Zl = fmaxf(Zl, __shfl_xor(Zl, m));
        logn += logf(Zl);
        c = cn * (1.0f / Zl);
        #pragma unroll
        for (int f = 0; f < 16; ++f) wb[f] = wn[f];
    }

    float dot = c * rb[j];
    #pragma unroll
    for (int m = 32; m; m >>= 1) dot += __shfl_xor(dot, m);
    if (j == 0) out[b] = 2.0f * (logn + logf(fabsf(dot)));
}

// ---------------- fallback (R2 kernel) if d_ws is too small ----------------
__global__ __launch_bounds__(256) void tt_transpose(
    const float* __restrict__ core, float* __restrict__ coreT)
{
    __shared__ float tile[64][65];
    const int x = blockIdx.x;
    const float* src = core + x * 4096;
    float* dst = coreT + x * 4096;
    const int r0 = threadIdx.x >> 6, cc = threadIdx.x & 63;
    #pragma unroll
    for (int k = 0; k < 16; ++k) tile[r0 + 4 * k][cc] = src[(r0 + 4 * k) * 64 + cc];
    __syncthreads();
    #pragma unroll
    for (int k = 0; k < 16; ++k) dst[(r0 + 4 * k) * 64 + cc] = tile[cc][r0 + 4 * k];
}

__global__ __launch_bounds__(64, 1) void ttrain_chain2(
    const int* __restrict__ X, const float* __restrict__ coreT,
    const float* __restrict__ lb, const float* __restrict__ rb,
    float* __restrict__ out)
{
    __shared__ float cbuf[2][64];
    const int b = blockIdx.x, j = threadIdx.x;
    const int* Xrow = X + b * TT_S;
    float c = lb[j];
    float Z = fabsf(c);
    #pragma unroll
    for (int m = 32; m; m >>= 1) Z = fmaxf(Z, __shfl_xor(Z, m));
    float logn = logf(Z);
    c *= (1.0f / Z);
    const float* colbase = coreT + j * 64;
    int xs_cur = Xrow[j];
    int xs_nxt = Xrow[64 + j];
    float4 wA[16], wB[16];
    {
        const int x0 = Xrow[0];
        const float4* p = (const float4*)(colbase + x0 * 4096);
        #pragma unroll
        for (int k = 0; k < 16; ++k) wA[k] = p[k];
    }
    #define TT_STEP(WCUR, WNXT, SLOT, XNEXT, T)                              \
    {                                                                        \
        cbuf[SLOT][j] = c;                                                   \
        {                                                                    \
            const float4* pre = (const float4*)(colbase + (XNEXT) * 4096);   \
            _Pragma("unroll")                                                \
            for (int k = 0; k < 16; ++k) WNXT[k] = pre[k];                   \
        }                                                                    \
        asm volatile("s_waitcnt lgkmcnt(0)" ::: "memory");                   \
        float a0 = 0.f, a1 = 0.f, a2 = 0.f, a3 = 0.f;                        \
        const float4* cb2 = (const float4*)cbuf[SLOT];                       \
        _Pragma("unroll")                                                    \
        for (int k = 0; k < 16; ++k) {                                       \
            float4 cv = cb2[k];                                              \
            a0 = fmaf(cv.x, WCUR[k].x, a0);                                  \
            a1 = fmaf(cv.y, WCUR[k].y, a1);                                  \
            a2 = fmaf(cv.z, WCUR[k].z, a2);                                  \
            a3 = fmaf(cv.w, WCUR[k].w, a3);                                  \
        }                                                                    \
        float cn = (a0 + a1) + (a2 + a3);                                    \
        if (((T) & 7) == 7) {                                                \
            float Zl = fabsf(cn);                                            \
            _Pragma("unroll")                                                \
            for (int m = 32; m; m >>= 1) Zl = fmaxf(Zl, __shfl_xor(Zl, m));  \
            logn += logf(Zl);                                                \
            cn *= (1.0f / Zl);                                               \
        }                                                                    \
        c = cn;                                                              \
    }
    for (int tc = 0; tc < TT_S; tc += 64) {
        #pragma unroll 1
        for (int u = 0; u < 64; u += 2) {
            const int x1 = __builtin_amdgcn_readlane(xs_cur, u + 1);
            TT_STEP(wA, wB, 0, x1, tc + u)
            const int src2 = (u + 2 < 64) ? xs_cur : xs_nxt;
            const int x2 = __builtin_amdgcn_readlane(src2, (u + 2) & 63);
            TT_STEP(wB, wA, 1, x2, tc + u + 1)
        }
        xs_cur = xs_nxt;
        const int nc = tc + 128;
        xs_nxt = Xrow[((nc < TT_S) ? nc : 0) + j];
    }
    #undef TT_STEP
    float dot = c * rb[j];
    #pragma unroll
    for (int m = 32; m; m >>= 1) dot += __shfl_xor(dot, m);
    if (j == 0) out[b] = 2.0f * (logn + logf(fabsf(dot)));
}

extern "C" void kernel_launch(void* const* d_in, const int* in_sizes, int n_in,
                              void* d_out, int out_size, void* d_ws, size_t ws_size,
                              hipStream_t stream) {
    const int*   X    = (const int*)d_in[0];    // [B, S] int32
    const float* core = (const float*)d_in[1];  // [d, D, D] fp32
    const float* lb   = (const float*)d_in[2];  // [D]
    const float* rb   = (const float*)d_in[3];  // [D]
    float* out = (float*)d_out;                 // [B]

    const int B = in_sizes[0] / TT_S;
    const size_t tblBytes = (size_t)64 * 8 * 64 * 8 * sizeof(short);  // 512KB each
    const size_t ptBytes  = (size_t)B * 16 * 4096 * sizeof(float);    // 32MB @B=128
    const size_t lnBytes  = (size_t)B * 16 * sizeof(float);
    const size_t need = 2 * tblBytes + ptBytes + lnBytes;

    if (ws_size >= need) {
        char* w = (char*)d_ws;
        short* tblA  = (short*)w;
        short* tblBt = (short*)(w + tblBytes);
        float* PT    = (float*)(w + 2 * tblBytes);
        float* ln1   = (float*)(w + 2 * tblBytes + ptBytes);
        tt_prep<<<64, 64, 0, stream>>>(core, tblA, tblBt);
        tt_stage1<<<B * 16, 64, 0, stream>>>(X, tblA, tblBt, PT, ln1);
        tt_stage2<<<B, 64, 0, stream>>>(PT, ln1, lb, rb, out);
    } else if (ws_size >= (size_t)64 * 4096 * sizeof(float)) {
        float* coreT = (float*)d_ws;
        tt_transpose<<<64, 256, 0, stream>>>(core, coreT);
        ttrain_chain2<<<B, TT_D, 0, stream>>>(X, coreT, lb, rb, out);
    }
}